// Round 1
// baseline (25.404 us; speedup 1.0000x reference)
//
#include <hip/hip_runtime.h>

// SAD similarity: out[b,n,m] = -sum_d |lhs[b,n,d] - rhs[b,m,d]|
// B=4, N=M=1024, D=64, fp32.
//
// Structure: 64x64 output tile per 256-thread block. Both input tiles staged
// in LDS transposed (d-major) so the inner-loop reads are ds_read_b128 along
// the n / m axes: 2 LDS reads feed 16 outputs x (sub + add-with-abs) = 32 VALU.
// LDS stride 68 dwords keeps reads 16B-aligned and breaks the bank alias
// (a-frag conflict-free, b-frag 2-way == free).

constexpr int D = 64;
constexpr int TILE = 64;
constexpr int LDS_STRIDE = 68; // dwords per d-row (64 + 4 pad, 16B aligned)

__global__ __launch_bounds__(256, 4)
void sad_sim_kernel(const float* __restrict__ lhs,
                    const float* __restrict__ rhs,
                    float* __restrict__ out,
                    int N, int M) {
    __shared__ float aT[D * LDS_STRIDE]; // aT[d * 68 + n_local]
    __shared__ float bT[D * LDS_STRIDE]; // bT[d * 68 + m_local]

    const int b   = blockIdx.z;
    const int n0  = blockIdx.y * TILE;
    const int m0  = blockIdx.x * TILE;
    const int tid = threadIdx.x;

    // ---- stage both 64x64 tiles, transposing to d-major ----
    // thread -> local row r = tid>>2 (0..63), d-chunk d0 = (tid&3)*16.
    // Wave covers 16 consecutive rows x full D: contiguous 4KB, coalesced f4.
    {
        const int r  = tid >> 2;
        const int d0 = (tid & 3) << 4;
        const float* ga = lhs + ((size_t)b * N + (n0 + r)) * D + d0;
        const float* gb = rhs + ((size_t)b * M + (m0 + r)) * D + d0;
#pragma unroll
        for (int c = 0; c < 4; ++c) {
            const float4 va = *reinterpret_cast<const float4*>(ga + c * 4);
            const float4 vb = *reinterpret_cast<const float4*>(gb + c * 4);
            const int d = d0 + c * 4;
            aT[(d + 0) * LDS_STRIDE + r] = va.x;
            aT[(d + 1) * LDS_STRIDE + r] = va.y;
            aT[(d + 2) * LDS_STRIDE + r] = va.z;
            aT[(d + 3) * LDS_STRIDE + r] = va.w;
            bT[(d + 0) * LDS_STRIDE + r] = vb.x;
            bT[(d + 1) * LDS_STRIDE + r] = vb.y;
            bT[(d + 2) * LDS_STRIDE + r] = vb.z;
            bT[(d + 3) * LDS_STRIDE + r] = vb.w;
        }
    }
    __syncthreads();

    // ---- compute: each thread owns a 4x4 output sub-tile ----
    const int tc = tid & 15;  // m group (0..15)
    const int tr = tid >> 4;  // n group (0..15)

    float acc[4][4];
#pragma unroll
    for (int i = 0; i < 4; ++i)
#pragma unroll
        for (int j = 0; j < 4; ++j) acc[i][j] = 0.f;

#pragma unroll 8
    for (int d = 0; d < D; ++d) {
        const float4 a4 = *reinterpret_cast<const float4*>(&aT[d * LDS_STRIDE + tr * 4]);
        const float4 b4 = *reinterpret_cast<const float4*>(&bT[d * LDS_STRIDE + tc * 4]);
        const float av[4] = {a4.x, a4.y, a4.z, a4.w};
        const float bv[4] = {b4.x, b4.y, b4.z, b4.w};
#pragma unroll
        for (int i = 0; i < 4; ++i)
#pragma unroll
            for (int j = 0; j < 4; ++j)
                acc[i][j] += fabsf(av[i] - bv[j]);
    }

    // ---- epilogue: negate, float4 stores along m (coalesced) ----
#pragma unroll
    for (int i = 0; i < 4; ++i) {
        float4 o;
        o.x = -acc[i][0];
        o.y = -acc[i][1];
        o.z = -acc[i][2];
        o.w = -acc[i][3];
        float* dst = out + (((size_t)b * N + n0 + tr * 4 + i) * M + m0 + tc * 4);
        *reinterpret_cast<float4*>(dst) = o;
    }
}

extern "C" void kernel_launch(void* const* d_in, const int* in_sizes, int n_in,
                              void* d_out, int out_size, void* d_ws, size_t ws_size,
                              hipStream_t stream) {
    const float* lhs = (const float*)d_in[0];
    const float* rhs = (const float*)d_in[1];
    float* out = (float*)d_out;

    // Recover B, N, M (D fixed at 64): in_sizes[0]=B*N*D, in_sizes[1]=B*M*D,
    // out_size=B*N*M.
    const long long bn = (long long)in_sizes[0] / D; // B*N
    const long long bm = (long long)in_sizes[1] / D; // B*M
    const int B = (int)((bn * bm) / (long long)out_size);
    const int N = (int)(bn / B);
    const int M = (int)(bm / B);

    dim3 grid(M / TILE, N / TILE, B);
    sad_sim_kernel<<<grid, 256, 0, stream>>>(lhs, rhs, out, N, M);
}